// Round 1
// baseline (844.772 us; speedup 1.0000x reference)
//
#include <hip/hip_runtime.h>
#include <math.h>

#define N_PER 25000
#define HID 256
#define E_PER 200000

typedef unsigned short ushort_t;
typedef __attribute__((ext_vector_type(8))) unsigned short ushort8v;
typedef __attribute__((ext_vector_type(4))) unsigned short ushort4v;
typedef __attribute__((ext_vector_type(8))) __bf16 bf16x8;
typedef __attribute__((ext_vector_type(4))) float floatx4;

__device__ __forceinline__ float bf2f(unsigned short u) {
    union { unsigned int i; float f; } c; c.i = ((unsigned int)u) << 16; return c.f;
}
__device__ __forceinline__ unsigned short f2bf(float f) {
    union { float f; unsigned int i; } c; c.f = f;
    unsigned int i = c.i;
    return (unsigned short)((i + 0x7FFFu + ((i >> 16) & 1u)) >> 16);
}

// ---------------- degree counting ----------------
__global__ void k_count(const int* __restrict__ es, const int* __restrict__ ed,
                        int* __restrict__ cnt_s, int* __restrict__ cnt_d) {
    int i = blockIdx.x * 256 + threadIdx.x;
    if (i >= 2 * E_PER) return;
    int et = i / E_PER;
    atomicAdd(&cnt_s[et * N_PER + es[i]], 1);
    atomicAdd(&cnt_d[et * N_PER + ed[i]], 1);
}

__global__ void k_scale(const int* __restrict__ cnt_s, const int* __restrict__ cnt_d,
                        float* __restrict__ cs, float* __restrict__ cd) {
    int i = blockIdx.x * 256 + threadIdx.x;
    if (i >= 2 * N_PER) return;
    cs[i] = rsqrtf(fmaxf((float)cnt_s[i], 1.f));
    cd[i] = rsqrtf(fmaxf((float)cnt_d[i], 1.f));
}

// ---------------- CSR build: scan + fill ----------------
__global__ __launch_bounds__(1024) void k_scan(const int* __restrict__ cnt,
                                               int* __restrict__ off, int* __restrict__ cur) {
    int et = blockIdx.x, t = threadIdx.x;
    const int* c = cnt + et * N_PER;
    int loc[25]; int tot = 0;
#pragma unroll
    for (int j = 0; j < 25; j++) {
        int idx = t * 25 + j;
        int v = (idx < N_PER) ? c[idx] : 0;
        loc[j] = tot; tot += v;
    }
    __shared__ int sb[1024];
    sb[t] = tot; __syncthreads();
    for (int d = 1; d < 1024; d <<= 1) {
        int v = (t >= d) ? sb[t - d] : 0;
        __syncthreads();
        sb[t] += v;
        __syncthreads();
    }
    int base = sb[t] - tot;
#pragma unroll
    for (int j = 0; j < 25; j++) {
        int idx = t * 25 + j;
        if (idx <= N_PER) {
            int val = base + loc[j];
            off[et * (N_PER + 1) + idx] = val;
            if (idx < N_PER) cur[et * N_PER + idx] = val;
        }
    }
}

__global__ void k_fill(const int* __restrict__ es, const int* __restrict__ ed,
                       int* __restrict__ cur, int* __restrict__ csr) {
    int i = blockIdx.x * 256 + threadIdx.x;
    if (i >= 2 * E_PER) return;
    int et = i / E_PER;
    int d = ed[i];
    int pos = atomicAdd(&cur[et * N_PER + d], 1);
    csr[et * E_PER + pos] = es[i];
}

// ---------------- weight convert (fp32 [K][N] -> bf16 [N][K]) ----------------
__global__ void k_convw(const float* __restrict__ pre, const float* __restrict__ post,
                        const float* __restrict__ qW, const float* __restrict__ kW,
                        const float* __restrict__ vW, const float* __restrict__ oW,
                        const float* __restrict__ w1, const float* __restrict__ w2,
                        ushort_t* __restrict__ out) {
    int i = blockIdx.x * 256 + threadIdx.x;
    if (i >= 1310720) return;
    float v;
    if (i < 786432) {                       // 12 matrices of 256x256
        int mat = i >> 16;                  // 0..11: pre0,pre1,post0,post1,q0,q1,k0,k1,v0,v1,o0,o1
        int e = i & 65535;
        int n = e >> 8, k = e & 255;        // WT[n][k]
        int tt = mat & 1, g = mat >> 1;
        const float* src = (g == 0) ? pre : (g == 1) ? post : (g == 2) ? qW :
                           (g == 3) ? kW : (g == 4) ? vW : oW;
        v = src[tt * 65536 + k * 256 + n];
    } else if (i < 1048576) {               // ffn_W1: [256][512] -> WT [512][256]
        int e = i - 786432; int tt = e >> 17; int r = e & 131071;
        int n = r >> 8, k = r & 255;
        v = w1[tt * 131072 + k * 512 + n];
    } else {                                // ffn_W2: [512][256] -> WT [256][512]
        int e = i - 1048576; int tt = e >> 17; int r = e & 131071;
        int n = r >> 9, k = r & 511;
        v = w2[tt * 131072 + k * 256 + n];
    }
    out[i] = f2bf(v);
}

// ---------------- LayerNorm (+optional cs scale) -> bf16 ----------------
__global__ __launch_bounds__(256) void k_ln(const float* __restrict__ h,
                                            const float* __restrict__ g, const float* __restrict__ b,
                                            const float* __restrict__ cs, ushort_t* __restrict__ out) {
    int lane = threadIdx.x & 63;
    int row = blockIdx.x * 4 + (threadIdx.x >> 6);    // 0..49999
    int ty = row >= N_PER;
    float4 x = *(const float4*)(h + (size_t)row * HID + lane * 4);
    float s = x.x + x.y + x.z + x.w;
    float q = x.x * x.x + x.y * x.y + x.z * x.z + x.w * x.w;
    for (int m = 1; m < 64; m <<= 1) {
        s += __shfl_xor(s, m, 64);
        q += __shfl_xor(q, m, 64);
    }
    float mean = s * (1.f / 256.f);
    float var = q * (1.f / 256.f) - mean * mean;
    float rs = rsqrtf(var + 1e-5f);
    float sc = cs ? cs[row] : 1.f;
    int c = lane * 4;
    const float* gp = g + ty * HID + c;
    const float* bp = b + ty * HID + c;
    float xv[4] = {x.x, x.y, x.z, x.w};
    ushort4v o;
#pragma unroll
    for (int i = 0; i < 4; i++) {
        float y = ((xv[i] - mean) * rs * gp[i] + bp[i]) * sc;
        o[i] = f2bf(y);
    }
    *(ushort4v*)(out + (size_t)row * HID + c) = o;
}

// ---------------- conv gather: agg[et][n] = sum_src hn_scaled[et][src] ----------------
__global__ __launch_bounds__(256) void k_gather(const ushort_t* __restrict__ hn,
                                                const int* __restrict__ off, const int* __restrict__ csr,
                                                ushort_t* __restrict__ agg) {
    int lane = threadIdx.x & 63;
    int row = blockIdx.x * 4 + (threadIdx.x >> 6);    // dst global id
    int dt = row >= N_PER;
    int n = row - dt * N_PER;
    int et = 1 - dt;                                   // src type == et
    int s0 = off[et * (N_PER + 1) + n], s1 = off[et * (N_PER + 1) + n + 1];
    const ushort_t* hb = hn + (size_t)et * N_PER * HID + lane * 4;
    const int* list = csr + et * E_PER;
    float a0 = 0, a1 = 0, a2 = 0, a3 = 0;
    for (int e = s0; e < s1; ++e) {
        int src = list[e];
        ushort4v u = *(const ushort4v*)(hb + (size_t)src * HID);
        a0 += bf2f(u[0]); a1 += bf2f(u[1]); a2 += bf2f(u[2]); a3 += bf2f(u[3]);
    }
    ushort4v o; o[0] = f2bf(a0); o[1] = f2bf(a1); o[2] = f2bf(a2); o[3] = f2bf(a3);
    *(ushort4v*)(agg + ((size_t)et * N_PER + n) * HID + lane * 4) = o;
}

// ---------------- fused edge softmax attention (online) ----------------
__global__ __launch_bounds__(256) void k_attn(const ushort_t* __restrict__ q,
                                              const ushort_t* __restrict__ k, const ushort_t* __restrict__ v,
                                              const int* __restrict__ off, const int* __restrict__ csr,
                                              ushort_t* __restrict__ outb) {
    int lane = threadIdx.x & 63;
    int row = blockIdx.x * 4 + (threadIdx.x >> 6);    // dst global id 0..49999
    int dt = row >= N_PER;
    int n = row - dt * N_PER;
    int et = 1 - dt;                                   // CSR etype; src type == et
    int s0 = off[et * (N_PER + 1) + n], s1 = off[et * (N_PER + 1) + n + 1];
    ushort4v qu = *(const ushort4v*)(q + (size_t)row * HID + lane * 4);
    float q0 = bf2f(qu[0]), q1 = bf2f(qu[1]), q2 = bf2f(qu[2]), q3 = bf2f(qu[3]);
    const ushort_t* kb = k + (size_t)et * N_PER * HID + lane * 4;
    const ushort_t* vb = v + (size_t)et * N_PER * HID + lane * 4;
    const int* list = csr + et * E_PER;
    float m = -INFINITY, l = 0.f;
    float O0 = 0, O1 = 0, O2 = 0, O3 = 0;
    for (int e = s0; e < s1; ++e) {
        int src = list[e];
        ushort4v ku = *(const ushort4v*)(kb + (size_t)src * HID);
        ushort4v vu = *(const ushort4v*)(vb + (size_t)src * HID);
        float d = q0 * bf2f(ku[0]) + q1 * bf2f(ku[1]) + q2 * bf2f(ku[2]) + q3 * bf2f(ku[3]);
        d += __shfl_xor(d, 1, 64);
        d += __shfl_xor(d, 2, 64);
        d += __shfl_xor(d, 4, 64);                     // full 32-dim head dot (8 lanes/head)
        float s = fminf(5.f, fmaxf(-5.f, d * 0.17677669529663687f));
        float nm = fmaxf(m, s);
        float c = __expf(m - nm);
        float p = __expf(s - nm);
        l = l * c + p;
        O0 = O0 * c + p * bf2f(vu[0]);
        O1 = O1 * c + p * bf2f(vu[1]);
        O2 = O2 * c + p * bf2f(vu[2]);
        O3 = O3 * c + p * bf2f(vu[3]);
        m = nm;
    }
    float inv = (l > 0.f) ? 1.f / l : 0.f;
    ushort4v o;
    o[0] = f2bf(O0 * inv); o[1] = f2bf(O1 * inv); o[2] = f2bf(O2 * inv); o[3] = f2bf(O3 * inv);
    *(ushort4v*)(outb + (size_t)row * HID + lane * 4) = o;
}

// ---------------- bf16 MFMA GEMM, 128x128x32 tiles ----------------
// MODE 0: h[zo] += acc*scale[z][m] + bias   (conv, zo = 1-z)
// MODE 1: h[z]  += acc + bias               (oproj / ffn2)
// MODE 2: outb  = bf16(acc + bias)          (q/k/v proj)
// MODE 3: outb  = bf16(gelu(acc + bias))    (ffn1)
template <int MODE>
__global__ __launch_bounds__(256) void k_gemm(const ushort_t* __restrict__ A, long Az,
                                              const ushort_t* __restrict__ BT, long Bz,
                                              const float* __restrict__ bias, int K,
                                              float* __restrict__ hout, int swapz,
                                              ushort_t* __restrict__ outb, long Oz,
                                              const float* __restrict__ scale) {
    __shared__ __align__(16) ushort_t Al[128 * 40];
    __shared__ __align__(16) ushort_t Bl[128 * 40];
    const int t = threadIdx.x;
    const int lane = t & 63, wid = t >> 6;
    const int wm = wid & 1, wn = wid >> 1;
    const int z = blockIdx.z;
    const int m0 = blockIdx.x * 128, n0 = blockIdx.y * 128;
    const int Ncols = gridDim.y * 128;

    const ushort_t* Ab = A + (long)z * Az;
    const ushort_t* Bb = BT + (long)z * Bz;

    floatx4 acc[4][4];
#pragma unroll
    for (int i = 0; i < 4; i++)
#pragma unroll
        for (int j = 0; j < 4; j++) acc[i][j] = (floatx4){0.f, 0.f, 0.f, 0.f};

    const int rA = t >> 2;              // 0..63
    const int cA = (t & 3) * 8;
    const int qo = (lane >> 4) * 8;
    const int ml = lane & 15;

    int nk = K >> 5;
    for (int kt = 0; kt < nk; ++kt) {
        int kb = kt * 32 + cA;
        ushort8v a0 = {0, 0, 0, 0, 0, 0, 0, 0}, a1 = a0;
        int gm0 = m0 + rA, gm1 = m0 + rA + 64;
        if (gm0 < N_PER) a0 = *(const ushort8v*)(Ab + (long)gm0 * K + kb);
        if (gm1 < N_PER) a1 = *(const ushort8v*)(Ab + (long)gm1 * K + kb);
        ushort8v b0 = *(const ushort8v*)(Bb + (long)(n0 + rA) * K + kb);
        ushort8v b1 = *(const ushort8v*)(Bb + (long)(n0 + rA + 64) * K + kb);
        __syncthreads();
        *(ushort8v*)(Al + rA * 40 + cA) = a0;
        *(ushort8v*)(Al + (rA + 64) * 40 + cA) = a1;
        *(ushort8v*)(Bl + rA * 40 + cA) = b0;
        *(ushort8v*)(Bl + (rA + 64) * 40 + cA) = b1;
        __syncthreads();
        bf16x8 af[4], bfr[4];
#pragma unroll
        for (int i = 0; i < 4; i++)
            af[i] = *(const bf16x8*)(Al + (wm * 64 + i * 16 + ml) * 40 + qo);
#pragma unroll
        for (int j = 0; j < 4; j++)
            bfr[j] = *(const bf16x8*)(Bl + (wn * 64 + j * 16 + ml) * 40 + qo);
#pragma unroll
        for (int i = 0; i < 4; i++)
#pragma unroll
            for (int j = 0; j < 4; j++)
                acc[i][j] = __builtin_amdgcn_mfma_f32_16x16x32_bf16(af[i], bfr[j], acc[i][j], 0, 0, 0);
    }

    const float* bz = bias + (long)z * Ncols;
    int zo = swapz ? (1 - z) : z;
#pragma unroll
    for (int i = 0; i < 4; i++) {
        int mb = m0 + wm * 64 + i * 16 + ((lane >> 4) << 2);
#pragma unroll
        for (int j = 0; j < 4; j++) {
            int col = n0 + wn * 64 + j * 16 + (lane & 15);
            float bv = bz[col];
#pragma unroll
            for (int r = 0; r < 4; r++) {
                int mm = mb + r;
                if (mm < N_PER) {
                    float vv = acc[i][j][r];
                    if (MODE == 0) vv = vv * scale[z * N_PER + mm] + bv;
                    else vv += bv;
                    if (MODE == 3) vv = 0.5f * vv * (1.0f + erff(vv * 0.70710678118654752f));
                    if (MODE <= 1) {
                        size_t idx = (size_t)zo * (N_PER * HID) + (size_t)mm * HID + col;
                        hout[idx] += vv;
                    } else {
                        size_t idx = (size_t)z * Oz + (size_t)mm * Ncols + col;
                        outb[idx] = f2bf(vv);
                    }
                }
            }
        }
    }
}

extern "C" void kernel_launch(void* const* d_in, const int* in_sizes, int n_in,
                              void* d_out, int out_size, void* d_ws, size_t ws_size,
                              hipStream_t stream) {
    const float* h_in   = (const float*)d_in[0];
    const int*   e_src  = (const int*)d_in[1];
    const int*   e_dst  = (const int*)d_in[2];
    const float* pre_W  = (const float*)d_in[3];
    const float* pre_b  = (const float*)d_in[4];
    const float* post_W = (const float*)d_in[5];
    const float* post_b = (const float*)d_in[6];
    const float* q_W    = (const float*)d_in[7];
    const float* q_b    = (const float*)d_in[8];
    const float* k_W    = (const float*)d_in[9];
    const float* k_b    = (const float*)d_in[10];
    const float* v_W    = (const float*)d_in[11];
    const float* v_b    = (const float*)d_in[12];
    const float* o_W    = (const float*)d_in[13];
    const float* o_b    = (const float*)d_in[14];
    const float* ffn_W1 = (const float*)d_in[15];
    const float* ffn_b1 = (const float*)d_in[16];
    const float* ffn_W2 = (const float*)d_in[17];
    const float* ffn_b2 = (const float*)d_in[18];
    const float* ln_pre_g  = (const float*)d_in[19];
    const float* ln_pre_b  = (const float*)d_in[20];
    const float* ln_attn_g = (const float*)d_in[21];
    const float* ln_attn_b = (const float*)d_in[22];
    const float* ln_post_g = (const float*)d_in[23];
    const float* ln_post_b = (const float*)d_in[24];
    const float* ln_ffn_g  = (const float*)d_in[25];
    const float* ln_ffn_b  = (const float*)d_in[26];

    float* hout = (float*)d_out;
    char* ws = (char*)d_ws;

    // workspace layout (bytes)
    ushort_t* hn   = (ushort_t*)(ws + 0);              // 25.6 MB  bf16 [2][25000][256]
    ushort_t* qb   = (ushort_t*)(ws + 25600000);       // 25.6 MB
    ushort_t* kb   = (ushort_t*)(ws + 51200000);       // 25.6 MB
    ushort_t* vb   = (ushort_t*)(ws + 76800000);       // 25.6 MB
    ushort_t* agg  = (ushort_t*)(ws + 102400000);      // 25.6 MB  (agg / attn_out)
    ushort_t* fb   = qb;                               // 51.2 MB alias over q+k (FFN only)
    ushort_t* wT   = (ushort_t*)(ws + 128000000);      // 2.62 MB
    float* cs      = (float*)(ws + 130621440);         // 200 KB
    float* cd      = (float*)(ws + 130821440);
    int* cnt_s     = (int*)(ws + 131021440);
    int* cnt_d     = (int*)(ws + 131221440);
    int* off       = (int*)(ws + 131421440);           // 2*25001 ints
    int* cur       = (int*)(ws + 131621448);
    int* csr       = (int*)(ws + 131821448);           // 2*200000 ints

    const ushort_t* preWT  = wT;
    const ushort_t* postWT = wT + 2 * 65536;
    const ushort_t* qWT    = wT + 4 * 65536;
    const ushort_t* kWT    = wT + 6 * 65536;
    const ushort_t* vWT    = wT + 8 * 65536;
    const ushort_t* oWT    = wT + 10 * 65536;
    const ushort_t* w1T    = wT + 786432;
    const ushort_t* w2T    = wT + 1048576;

    const long AzH = (long)N_PER * HID;   // 6.4M elems

    // h accumulator = d_out, init with input h
    hipMemcpyAsync(hout, h_in, (size_t)2 * N_PER * HID * sizeof(float),
                   hipMemcpyDeviceToDevice, stream);
    hipMemsetAsync(cnt_s, 0, 400000, stream);   // cnt_s + cnt_d contiguous

    k_convw<<<5120, 256, 0, stream>>>(pre_W, post_W, q_W, k_W, v_W, o_W, ffn_W1, ffn_W2, wT);
    k_count<<<1563, 256, 0, stream>>>(e_src, e_dst, cnt_s, cnt_d);
    k_scale<<<196, 256, 0, stream>>>(cnt_s, cnt_d, cs, cd);
    k_scan<<<2, 1024, 0, stream>>>(cnt_d, off, cur);
    k_fill<<<1563, 256, 0, stream>>>(e_src, e_dst, cur, csr);

    // ---- stage 1: pre hetero-conv ----
    k_ln<<<12500, 256, 0, stream>>>(hout, ln_pre_g, ln_pre_b, cs, hn);
    k_gather<<<12500, 256, 0, stream>>>(hn, off, csr, agg);
    k_gemm<0><<<dim3(196, 2, 2), 256, 0, stream>>>(agg, AzH, preWT, 65536, pre_b, 256,
                                                   hout, 1, (ushort_t*)nullptr, 0, cd);

    // ---- stage 2: sparse attention ----
    k_ln<<<12500, 256, 0, stream>>>(hout, ln_attn_g, ln_attn_b, (const float*)nullptr, hn);
    k_gemm<2><<<dim3(196, 2, 2), 256, 0, stream>>>(hn, AzH, qWT, 65536, q_b, 256,
                                                   (float*)nullptr, 0, qb, AzH, (const float*)nullptr);
    k_gemm<2><<<dim3(196, 2, 2), 256, 0, stream>>>(hn, AzH, kWT, 65536, k_b, 256,
                                                   (float*)nullptr, 0, kb, AzH, (const float*)nullptr);
    k_gemm<2><<<dim3(196, 2, 2), 256, 0, stream>>>(hn, AzH, vWT, 65536, v_b, 256,
                                                   (float*)nullptr, 0, vb, AzH, (const float*)nullptr);
    k_attn<<<12500, 256, 0, stream>>>(qb, kb, vb, off, csr, agg);
    k_gemm<1><<<dim3(196, 2, 2), 256, 0, stream>>>(agg, AzH, oWT, 65536, o_b, 256,
                                                   hout, 0, (ushort_t*)nullptr, 0, (const float*)nullptr);

    // ---- stage 3: post hetero-conv ----
    k_ln<<<12500, 256, 0, stream>>>(hout, ln_post_g, ln_post_b, cs, hn);
    k_gather<<<12500, 256, 0, stream>>>(hn, off, csr, agg);
    k_gemm<0><<<dim3(196, 2, 2), 256, 0, stream>>>(agg, AzH, postWT, 65536, post_b, 256,
                                                   hout, 1, (ushort_t*)nullptr, 0, cd);

    // ---- stage 4: FFN ----
    k_ln<<<12500, 256, 0, stream>>>(hout, ln_ffn_g, ln_ffn_b, (const float*)nullptr, hn);
    k_gemm<3><<<dim3(196, 4, 2), 256, 0, stream>>>(hn, AzH, w1T, 131072, ffn_b1, 256,
                                                   (float*)nullptr, 0, fb, (long)N_PER * 512, (const float*)nullptr);
    k_gemm<1><<<dim3(196, 2, 2), 256, 0, stream>>>(fb, (long)N_PER * 512, w2T, 131072, ffn_b2, 512,
                                                   hout, 0, (ushort_t*)nullptr, 0, (const float*)nullptr);
}

// Round 2
// 777.286 us; speedup vs baseline: 1.0868x; 1.0868x over previous
//
#include <hip/hip_runtime.h>
#include <math.h>

#define N_PER 25000
#define HID 256
#define E_PER 200000

typedef unsigned short ushort_t;
typedef __attribute__((ext_vector_type(8))) unsigned short ushort8v;
typedef __attribute__((ext_vector_type(4))) unsigned short ushort4v;
typedef __attribute__((ext_vector_type(8))) __bf16 bf16x8;
typedef __attribute__((ext_vector_type(4))) float floatx4;

__device__ __forceinline__ float bf2f(unsigned short u) {
    union { unsigned int i; float f; } c; c.i = ((unsigned int)u) << 16; return c.f;
}
__device__ __forceinline__ unsigned short f2bf(float f) {
    union { float f; unsigned int i; } c; c.f = f;
    unsigned int i = c.i;
    return (unsigned short)((i + 0x7FFFu + ((i >> 16) & 1u)) >> 16);
}

// ---------------- degree counting ----------------
__global__ void k_count(const int* __restrict__ es, const int* __restrict__ ed,
                        int* __restrict__ cnt_s, int* __restrict__ cnt_d) {
    int i = blockIdx.x * 256 + threadIdx.x;
    if (i >= 2 * E_PER) return;
    int et = i / E_PER;
    atomicAdd(&cnt_s[et * N_PER + es[i]], 1);
    atomicAdd(&cnt_d[et * N_PER + ed[i]], 1);
}

__global__ void k_scale(const int* __restrict__ cnt_s, const int* __restrict__ cnt_d,
                        float* __restrict__ cs, float* __restrict__ cd) {
    int i = blockIdx.x * 256 + threadIdx.x;
    if (i >= 2 * N_PER) return;
    cs[i] = rsqrtf(fmaxf((float)cnt_s[i], 1.f));
    cd[i] = rsqrtf(fmaxf((float)cnt_d[i], 1.f));
}

// ---------------- CSR build: scan + fill ----------------
__global__ __launch_bounds__(1024) void k_scan(const int* __restrict__ cnt,
                                               int* __restrict__ off, int* __restrict__ cur) {
    int et = blockIdx.x, t = threadIdx.x;
    const int* c = cnt + et * N_PER;
    int loc[25]; int tot = 0;
#pragma unroll
    for (int j = 0; j < 25; j++) {
        int idx = t * 25 + j;
        int v = (idx < N_PER) ? c[idx] : 0;
        loc[j] = tot; tot += v;
    }
    __shared__ int sb[1024];
    sb[t] = tot; __syncthreads();
    for (int d = 1; d < 1024; d <<= 1) {
        int v = (t >= d) ? sb[t - d] : 0;
        __syncthreads();
        sb[t] += v;
        __syncthreads();
    }
    int base = sb[t] - tot;
#pragma unroll
    for (int j = 0; j < 25; j++) {
        int idx = t * 25 + j;
        if (idx <= N_PER) {
            int val = base + loc[j];
            off[et * (N_PER + 1) + idx] = val;
            if (idx < N_PER) cur[et * N_PER + idx] = val;
        }
    }
}

__global__ void k_fill(const int* __restrict__ es, const int* __restrict__ ed,
                       int* __restrict__ cur, int* __restrict__ csr) {
    int i = blockIdx.x * 256 + threadIdx.x;
    if (i >= 2 * E_PER) return;
    int et = i / E_PER;
    int d = ed[i];
    int pos = atomicAdd(&cur[et * N_PER + d], 1);
    csr[et * E_PER + pos] = es[i];
}

// ---------------- weight convert (fp32 [K][N] -> bf16 [N][K], new layout) ----------
// layout (elems): pre[2][256][256] @0, post @131072, qkv[2][768][256] @262144,
//                 o @655360, w1[2][512][256] @786432, w2[2][256][512] @1048576
__global__ void k_convw(const float* __restrict__ pre, const float* __restrict__ post,
                        const float* __restrict__ qW, const float* __restrict__ kW,
                        const float* __restrict__ vW, const float* __restrict__ oW,
                        const float* __restrict__ w1, const float* __restrict__ w2,
                        ushort_t* __restrict__ out) {
    int i = blockIdx.x * 256 + threadIdx.x;
    if (i >= 1310720) return;
    float v;
    if (i < 131072) {
        int z = i >> 16, n = (i >> 8) & 255, k = i & 255;
        v = pre[z * 65536 + k * 256 + n];
    } else if (i < 262144) {
        int j = i - 131072; int z = j >> 16, n = (j >> 8) & 255, k = j & 255;
        v = post[z * 65536 + k * 256 + n];
    } else if (i < 655360) {
        int j = i - 262144;
        int z = (j >= 196608) ? 1 : 0;
        int r = j - z * 196608;
        int row = r >> 8, k = r & 255;
        int mat = row >> 8, c = row & 255;
        const float* src = (mat == 0) ? qW : (mat == 1) ? kW : vW;
        v = src[z * 65536 + k * 256 + c];
    } else if (i < 786432) {
        int j = i - 655360; int z = j >> 16, n = (j >> 8) & 255, k = j & 255;
        v = oW[z * 65536 + k * 256 + n];
    } else if (i < 1048576) {
        int j = i - 786432; int z = j >> 17, r = j & 131071;
        int n = r >> 8, k = r & 255;
        v = w1[z * 131072 + k * 512 + n];
    } else {
        int j = i - 1048576; int z = j >> 17, r = j & 131071;
        int n = r >> 9, k = r & 511;
        v = w2[z * 131072 + k * 256 + n];
    }
    out[i] = f2bf(v);
}

// pack q/k/v biases -> [2][768]
__global__ void k_packbias(const float* __restrict__ qb, const float* __restrict__ kb,
                           const float* __restrict__ vb, float* __restrict__ out) {
    int i = blockIdx.x * 256 + threadIdx.x;
    if (i >= 1536) return;
    int z = i / 768, c = i % 768;
    int mat = c >> 8, cc = c & 255;
    const float* src = (mat == 0) ? qb : (mat == 1) ? kb : vb;
    out[i] = src[z * 256 + cc];
}

// ---------------- LayerNorm (+optional cs scale) -> bf16 ----------------
__global__ __launch_bounds__(256) void k_ln(const float* __restrict__ h,
                                            const float* __restrict__ g, const float* __restrict__ b,
                                            const float* __restrict__ cs, ushort_t* __restrict__ out) {
    int lane = threadIdx.x & 63;
    int row = blockIdx.x * 4 + (threadIdx.x >> 6);
    int ty = row >= N_PER;
    float4 x = *(const float4*)(h + (size_t)row * HID + lane * 4);
    float s = x.x + x.y + x.z + x.w;
    float q = x.x * x.x + x.y * x.y + x.z * x.z + x.w * x.w;
    for (int m = 1; m < 64; m <<= 1) {
        s += __shfl_xor(s, m, 64);
        q += __shfl_xor(q, m, 64);
    }
    float mean = s * (1.f / 256.f);
    float var = q * (1.f / 256.f) - mean * mean;
    float rs = rsqrtf(var + 1e-5f);
    float sc = cs ? cs[row] : 1.f;
    int c = lane * 4;
    const float* gp = g + ty * HID + c;
    const float* bp = b + ty * HID + c;
    float xv[4] = {x.x, x.y, x.z, x.w};
    ushort4v o;
#pragma unroll
    for (int i = 0; i < 4; i++) {
        float y = ((xv[i] - mean) * rs * gp[i] + bp[i]) * sc;
        o[i] = f2bf(y);
    }
    *(ushort4v*)(out + (size_t)row * HID + c) = o;
}

// residual add + LayerNorm: hnew = base + delta (fp32); out = bf16(LN(hnew)*cs)
__global__ __launch_bounds__(256) void k_lnadd(const float* __restrict__ base,
                                               const float* __restrict__ delta,
                                               const float* __restrict__ g, const float* __restrict__ b,
                                               const float* __restrict__ cs,
                                               float* __restrict__ hnew, ushort_t* __restrict__ out) {
    int lane = threadIdx.x & 63;
    int row = blockIdx.x * 4 + (threadIdx.x >> 6);
    int ty = row >= N_PER;
    size_t o4 = (size_t)row * HID + lane * 4;
    float4 x = *(const float4*)(base + o4);
    float4 d = *(const float4*)(delta + o4);
    x.x += d.x; x.y += d.y; x.z += d.z; x.w += d.w;
    float s = x.x + x.y + x.z + x.w;
    float q = x.x * x.x + x.y * x.y + x.z * x.z + x.w * x.w;
    for (int m = 1; m < 64; m <<= 1) {
        s += __shfl_xor(s, m, 64);
        q += __shfl_xor(q, m, 64);
    }
    float mean = s * (1.f / 256.f);
    float var = q * (1.f / 256.f) - mean * mean;
    float rs = rsqrtf(var + 1e-5f);
    float sc = cs ? cs[row] : 1.f;
    *(float4*)(hnew + o4) = x;
    int c = lane * 4;
    const float* gp = g + ty * HID + c;
    const float* bp = b + ty * HID + c;
    float xv[4] = {x.x, x.y, x.z, x.w};
    ushort4v o;
#pragma unroll
    for (int i = 0; i < 4; i++) {
        float y = ((xv[i] - mean) * rs * gp[i] + bp[i]) * sc;
        o[i] = f2bf(y);
    }
    *(ushort4v*)(out + (size_t)row * HID + c) = o;
}

// ---------------- conv gather: agg[et][n] = sum_src hn_scaled[et][src] ----------------
__global__ __launch_bounds__(256) void k_gather(const ushort_t* __restrict__ hn,
                                                const int* __restrict__ off, const int* __restrict__ csr,
                                                ushort_t* __restrict__ agg) {
    int lane = threadIdx.x & 63;
    int row = blockIdx.x * 4 + (threadIdx.x >> 6);
    int dt = row >= N_PER;
    int n = row - dt * N_PER;
    int et = 1 - dt;
    int s0 = off[et * (N_PER + 1) + n], s1 = off[et * (N_PER + 1) + n + 1];
    const ushort_t* hb = hn + (size_t)et * N_PER * HID + lane * 4;
    const int* list = csr + et * E_PER;
    float a0 = 0, a1 = 0, a2 = 0, a3 = 0;
    for (int e = s0; e < s1; ++e) {
        int src = list[e];
        ushort4v u = *(const ushort4v*)(hb + (size_t)src * HID);
        a0 += bf2f(u[0]); a1 += bf2f(u[1]); a2 += bf2f(u[2]); a3 += bf2f(u[3]);
    }
    ushort4v o; o[0] = f2bf(a0); o[1] = f2bf(a1); o[2] = f2bf(a2); o[3] = f2bf(a3);
    *(ushort4v*)(agg + ((size_t)et * N_PER + n) * HID + lane * 4) = o;
}

// ---------------- fused edge softmax attention (no running max: s clipped to +-5) ----
__global__ __launch_bounds__(256) void k_attn(const ushort_t* __restrict__ q,
                                              const ushort_t* __restrict__ k, const ushort_t* __restrict__ v,
                                              const int* __restrict__ off, const int* __restrict__ csr,
                                              ushort_t* __restrict__ outb) {
    int lane = threadIdx.x & 63;
    int row = blockIdx.x * 4 + (threadIdx.x >> 6);
    int dt = row >= N_PER;
    int n = row - dt * N_PER;
    int et = 1 - dt;
    int s0 = off[et * (N_PER + 1) + n], s1 = off[et * (N_PER + 1) + n + 1];
    ushort4v qu = *(const ushort4v*)(q + (size_t)row * HID + lane * 4);
    float q0 = bf2f(qu[0]), q1 = bf2f(qu[1]), q2 = bf2f(qu[2]), q3 = bf2f(qu[3]);
    const ushort_t* kb = k + (size_t)et * N_PER * HID + lane * 4;
    const ushort_t* vb = v + (size_t)et * N_PER * HID + lane * 4;
    const int* list = csr + et * E_PER;
    float l = 0.f;
    float O0 = 0, O1 = 0, O2 = 0, O3 = 0;
    for (int e = s0; e < s1; ++e) {
        int src = list[e];
        ushort4v ku = *(const ushort4v*)(kb + (size_t)src * HID);
        ushort4v vu = *(const ushort4v*)(vb + (size_t)src * HID);
        float d = q0 * bf2f(ku[0]) + q1 * bf2f(ku[1]) + q2 * bf2f(ku[2]) + q3 * bf2f(ku[3]);
        d += __shfl_xor(d, 1, 64);
        d += __shfl_xor(d, 2, 64);
        d += __shfl_xor(d, 4, 64);                    // 32-dim head dot (8 lanes/head)
        float s = fminf(5.f, fmaxf(-5.f, d * 0.17677669529663687f));
        float p = __expf(s);                          // safe: s in [-5,5]
        l += p;
        O0 += p * bf2f(vu[0]);
        O1 += p * bf2f(vu[1]);
        O2 += p * bf2f(vu[2]);
        O3 += p * bf2f(vu[3]);
    }
    float inv = (l > 0.f) ? 1.f / l : 0.f;
    ushort4v o;
    o[0] = f2bf(O0 * inv); o[1] = f2bf(O1 * inv); o[2] = f2bf(O2 * inv); o[3] = f2bf(O3 * inv);
    *(ushort4v*)(outb + (size_t)row * HID + lane * 4) = o;
}

// ---------------- B-resident-in-LDS MFMA GEMM ----------------
// block = 128 rows x 64 cols; B[64 cols][K<=256 chunk] in LDS; no barriers in K-loop.
// MODE 0: delta fp32 = acc*scale[z][m] + bias, written at type zo=1-z (conv)
// MODE 1: hout[z] += acc + bias (fp32 RMW, final ffn2)
// MODE 2: delta fp32 = acc + bias (o-proj)
// MODE 3: fb bf16 = gelu(acc + bias), row stride 512 (ffn1)
// MODE 4: qkv bf16 split by col>>8 (fused q/k/v)
template <int MODE>
__global__ __launch_bounds__(256) void k_gemm2(const ushort_t* __restrict__ A, long Az,
                                               const ushort_t* __restrict__ BT, long Bz,
                                               const float* __restrict__ bias, int K, int Ncols,
                                               float* __restrict__ foutp, int swapz,
                                               ushort_t* __restrict__ boutp,
                                               const float* __restrict__ scale) {
    __shared__ __align__(16) ushort_t Bl[64 * 264];   // stride 264: 2-way max on b128 reads
    const int t = threadIdx.x;
    const int lane = t & 63, w = t >> 6;
    const int z = blockIdx.z;
    const int m0 = blockIdx.x * 128, n0 = blockIdx.y * 64;
    const int ml = lane & 15, qo8 = (lane >> 4) * 8;
    const ushort_t* Ab = A + (long)z * Az;
    const ushort_t* Bb = BT + (long)z * Bz;

    floatx4 acc[2][4];
#pragma unroll
    for (int i = 0; i < 2; i++)
#pragma unroll
        for (int j = 0; j < 4; j++) acc[i][j] = (floatx4){0.f, 0.f, 0.f, 0.f};

    const int row0 = m0 + w * 32 + ml;
    const int row1 = row0 + 16;
    const ushort8v z8 = {0, 0, 0, 0, 0, 0, 0, 0};

    for (int k0 = 0; k0 < K; k0 += 256) {
        if (k0) __syncthreads();
        // stage B chunk: 64 cols x 256 k
#pragma unroll
        for (int i = 0; i < 8; i++) {
            int slot = t * 8 + i;
            int col = slot >> 5, kv = (slot & 31) * 8;
            *(ushort8v*)(Bl + col * 264 + kv) =
                *(const ushort8v*)(Bb + (long)(n0 + col) * K + k0 + kv);
        }
        __syncthreads();
#pragma unroll
        for (int kt = 0; kt < 8; kt++) {
            int kk = k0 + kt * 32 + qo8;
            ushort8v a0u = (row0 < N_PER) ? *(const ushort8v*)(Ab + (long)row0 * K + kk) : z8;
            ushort8v a1u = (row1 < N_PER) ? *(const ushort8v*)(Ab + (long)row1 * K + kk) : z8;
#pragma unroll
            for (int j = 0; j < 4; j++) {
                bf16x8 bfr = *(const bf16x8*)(Bl + (j * 16 + ml) * 264 + kt * 32 + qo8);
                acc[0][j] = __builtin_amdgcn_mfma_f32_16x16x32_bf16(*(bf16x8*)&a0u, bfr, acc[0][j], 0, 0, 0);
                acc[1][j] = __builtin_amdgcn_mfma_f32_16x16x32_bf16(*(bf16x8*)&a1u, bfr, acc[1][j], 0, 0, 0);
            }
        }
    }

    // epilogue
    const int zo = swapz ? 1 - z : z;
    float bv[4];
#pragma unroll
    for (int j = 0; j < 4; j++) bv[j] = bias[z * Ncols + n0 + j * 16 + ml];
    float sc[2][4];
    if (MODE == 0) {
#pragma unroll
        for (int i = 0; i < 2; i++)
#pragma unroll
            for (int r = 0; r < 4; r++) {
                int m = m0 + w * 32 + i * 16 + ((lane >> 4) << 2) + r;
                sc[i][r] = (m < N_PER) ? scale[z * N_PER + m] : 0.f;
            }
    }
#pragma unroll
    for (int i = 0; i < 2; i++) {
        int mb = m0 + w * 32 + i * 16 + ((lane >> 4) << 2);
#pragma unroll
        for (int j = 0; j < 4; j++) {
            int col = n0 + j * 16 + ml;
#pragma unroll
            for (int r = 0; r < 4; r++) {
                int m = mb + r;
                if (m >= N_PER) continue;
                float vv = acc[i][j][r];
                if (MODE == 0) vv = vv * sc[i][r] + bv[j];
                else vv += bv[j];
                if (MODE == 3) vv = 0.5f * vv * (1.0f + erff(vv * 0.70710678118654752f));
                if (MODE == 0 || MODE == 2) {
                    foutp[((size_t)zo * N_PER + m) * 256 + col] = vv;
                } else if (MODE == 1) {
                    foutp[((size_t)z * N_PER + m) * 256 + col] += vv;
                } else if (MODE == 3) {
                    boutp[((size_t)z * N_PER + m) * 512 + col] = f2bf(vv);
                } else {  // MODE 4
                    int mat = col >> 8, c = col & 255;
                    boutp[(size_t)mat * (2L * N_PER * 256) + ((size_t)z * N_PER + m) * 256 + c] = f2bf(vv);
                }
            }
        }
    }
}

extern "C" void kernel_launch(void* const* d_in, const int* in_sizes, int n_in,
                              void* d_out, int out_size, void* d_ws, size_t ws_size,
                              hipStream_t stream) {
    const float* h_in   = (const float*)d_in[0];
    const int*   e_src  = (const int*)d_in[1];
    const int*   e_dst  = (const int*)d_in[2];
    const float* pre_W  = (const float*)d_in[3];
    const float* pre_b  = (const float*)d_in[4];
    const float* post_W = (const float*)d_in[5];
    const float* post_b = (const float*)d_in[6];
    const float* q_W    = (const float*)d_in[7];
    const float* q_b    = (const float*)d_in[8];
    const float* k_W    = (const float*)d_in[9];
    const float* k_b    = (const float*)d_in[10];
    const float* v_W    = (const float*)d_in[11];
    const float* v_b    = (const float*)d_in[12];
    const float* o_W    = (const float*)d_in[13];
    const float* o_b    = (const float*)d_in[14];
    const float* ffn_W1 = (const float*)d_in[15];
    const float* ffn_b1 = (const float*)d_in[16];
    const float* ffn_W2 = (const float*)d_in[17];
    const float* ffn_b2 = (const float*)d_in[18];
    const float* ln_pre_g  = (const float*)d_in[19];
    const float* ln_pre_b  = (const float*)d_in[20];
    const float* ln_attn_g = (const float*)d_in[21];
    const float* ln_attn_b = (const float*)d_in[22];
    const float* ln_post_g = (const float*)d_in[23];
    const float* ln_post_b = (const float*)d_in[24];
    const float* ln_ffn_g  = (const float*)d_in[25];
    const float* ln_ffn_b  = (const float*)d_in[26];

    float* hout = (float*)d_out;
    char* ws = (char*)d_ws;

    const long AzH = (long)N_PER * HID;                 // 6.4M elems

    // workspace layout (bytes)
    ushort_t* hn    = (ushort_t*)(ws + 0);              // 25.6 MB bf16 [2][25000][256]
    ushort_t* qkv   = (ushort_t*)(ws + 25600000);       // 76.8 MB bf16 [3][2][25000][256]
    float*    deltab= (float*)(ws + 25600000);          // 51.2 MB fp32 delta (aliases q+k)
    ushort_t* fb    = (ushort_t*)(ws + 25600000);       // 51.2 MB bf16 [2][25000][512] (aliases q+k)
    ushort_t* agg   = (ushort_t*)(ws + 102400000);      // 25.6 MB
    ushort_t* wT    = (ushort_t*)(ws + 128000000);      // 2.62 MB
    float* qkvbias  = (float*)(ws + 130621440);         // 6 KB
    float* cs       = (float*)(ws + 130627584);
    float* cd       = (float*)(ws + 130827584);
    int* cnt_s      = (int*)(ws + 131027584);
    int* cnt_d      = (int*)(ws + 131227584);
    int* off        = (int*)(ws + 131427584);
    int* cur        = (int*)(ws + 131627592);
    int* csr        = (int*)(ws + 131827592);

    const ushort_t* preWT  = wT;
    const ushort_t* postWT = wT + 131072;
    const ushort_t* qkvWT  = wT + 262144;
    const ushort_t* oWT    = wT + 655360;
    const ushort_t* w1T    = wT + 786432;
    const ushort_t* w2T    = wT + 1048576;
    ushort_t* qb = qkv;                                  // [2][N][256]
    ushort_t* kb = qkv + 2 * AzH;
    ushort_t* vb = qkv + 4 * AzH;

    hipMemsetAsync(cnt_s, 0, 400000, stream);            // cnt_s + cnt_d contiguous

    k_convw<<<5120, 256, 0, stream>>>(pre_W, post_W, q_W, k_W, v_W, o_W, ffn_W1, ffn_W2, wT);
    k_packbias<<<6, 256, 0, stream>>>(q_b, k_b, v_b, qkvbias);
    k_count<<<1563, 256, 0, stream>>>(e_src, e_dst, cnt_s, cnt_d);
    k_scale<<<196, 256, 0, stream>>>(cnt_s, cnt_d, cs, cd);
    k_scan<<<2, 1024, 0, stream>>>(cnt_d, off, cur);
    k_fill<<<1563, 256, 0, stream>>>(e_src, e_dst, cur, csr);

    // ---- stage 1: pre hetero-conv ----
    k_ln<<<12500, 256, 0, stream>>>(h_in, ln_pre_g, ln_pre_b, cs, hn);
    k_gather<<<12500, 256, 0, stream>>>(hn, off, csr, agg);
    k_gemm2<0><<<dim3(196, 4, 2), 256, 0, stream>>>(agg, AzH, preWT, 65536, pre_b, 256, 256,
                                                    deltab, 1, (ushort_t*)nullptr, cd);

    // ---- stage 2: sparse attention ----
    k_lnadd<<<12500, 256, 0, stream>>>(h_in, deltab, ln_attn_g, ln_attn_b,
                                       (const float*)nullptr, hout, hn);
    k_gemm2<4><<<dim3(196, 12, 2), 256, 0, stream>>>(hn, AzH, qkvWT, 196608, qkvbias, 256, 768,
                                                     (float*)nullptr, 0, qkv, (const float*)nullptr);
    k_attn<<<12500, 256, 0, stream>>>(qb, kb, vb, off, csr, agg);
    k_gemm2<2><<<dim3(196, 4, 2), 256, 0, stream>>>(agg, AzH, oWT, 65536, o_b, 256, 256,
                                                    deltab, 0, (ushort_t*)nullptr, (const float*)nullptr);

    // ---- stage 3: post hetero-conv ----
    k_lnadd<<<12500, 256, 0, stream>>>(hout, deltab, ln_post_g, ln_post_b, cs, hout, hn);
    k_gather<<<12500, 256, 0, stream>>>(hn, off, csr, agg);
    k_gemm2<0><<<dim3(196, 4, 2), 256, 0, stream>>>(agg, AzH, postWT, 65536, post_b, 256, 256,
                                                    deltab, 1, (ushort_t*)nullptr, cd);

    // ---- stage 4: FFN ----
    k_lnadd<<<12500, 256, 0, stream>>>(hout, deltab, ln_ffn_g, ln_ffn_b,
                                       (const float*)nullptr, hout, hn);
    k_gemm2<3><<<dim3(196, 8, 2), 256, 0, stream>>>(hn, AzH, w1T, 131072, ffn_b1, 256, 512,
                                                    (float*)nullptr, 0, fb, (const float*)nullptr);
    k_gemm2<1><<<dim3(196, 4, 2), 256, 0, stream>>>(fb, (long)N_PER * 512, w2T, 131072, ffn_b2, 512, 256,
                                                    hout, 0, (ushort_t*)nullptr, (const float*)nullptr);
}